// Round 1
// baseline (329.336 us; speedup 1.0000x reference)
//
#include <hip/hip_runtime.h>
#include <hip/hip_bf16.h>
#include <cstdint>
#include <cstddef>

typedef __hip_bfloat16 bf16;
typedef __attribute__((ext_vector_type(8))) short bf16x8;
typedef __attribute__((ext_vector_type(4))) float f32x4;

#define AS1C(p) ((const __attribute__((address_space(1))) void*)(p))
#define AS3(p)  ((__attribute__((address_space(3))) void*)(p))

constexpr int B_ = 2, S_ = 2048, E_ = 1024, H_ = 16, D_ = 64;
constexpr int M_ = B_ * S_;        // 4096
constexpr float SCALE_ = 0.125f;   // 1/sqrt(64)

__device__ __forceinline__ void gload_lds16(const bf16* g, bf16* l) {
  __builtin_amdgcn_global_load_lds(AS1C(g), AS3(l), 16, 0, 0);
}

// ---------------- cast f32 -> bf16, 4 elems/thread ----------------
__global__ void cast_kernel(const float* __restrict__ in, bf16* __restrict__ out, int n4) {
  int i = blockIdx.x * blockDim.x + threadIdx.x;
  if (i >= n4) return;
  float4 v = reinterpret_cast<const float4*>(in)[i];
  union { bf16 b[4]; short4 s; } u;
  u.b[0] = __float2bfloat16(v.x);
  u.b[1] = __float2bfloat16(v.y);
  u.b[2] = __float2bfloat16(v.z);
  u.b[3] = __float2bfloat16(v.w);
  reinterpret_cast<short4*>(out)[i] = u.s;
}

// ---------------- RoPE sin/cos tables: [S][32] ----------------
__global__ void rope_table_kernel(float* __restrict__ sintab, float* __restrict__ costab) {
  int idx = blockIdx.x * blockDim.x + threadIdx.x;  // S_*32 total
  int s = idx >> 5, i = idx & 31;
  float inv = powf(10000.0f, -(float)i / 32.0f);
  float ang = (float)s * inv;
  sintab[idx] = sinf(ang);
  costab[idx] = cosf(ang);
}

// ---------------- GEMM: C = A(M x 1024) * W^T (W is N x K) + bias ----------------
// ROPE: apply rotary to output (pairs are adjacent columns; partner in lane^1)
// SCATTER: write bf16 to [b][h][s][d]; else write f32 to [m][n] (d_out)
template<bool ROPE, bool SCATTER>
__global__ __launch_bounds__(256)
void gemm_kernel(const bf16* __restrict__ A, const bf16* __restrict__ W,
                 const float* __restrict__ bias,
                 bf16* __restrict__ outS, float* __restrict__ outF,
                 const float* __restrict__ sintab, const float* __restrict__ costab)
{
  constexpr int K = 1024, BK = 32;
  __shared__ __align__(16) bf16 As[128 * BK];
  __shared__ __align__(16) bf16 Bs[128 * BK];
  const int tid = threadIdx.x;
  const int lane = tid & 63, wid = tid >> 6;
  const int g = lane >> 4, r16 = lane & 15;
  const int wr = wid >> 1, wc = wid & 1;
  const int m0 = blockIdx.y * 128, n0 = blockIdx.x * 128;

  const f32x4 fz = {0.f, 0.f, 0.f, 0.f};
  f32x4 acc[4][4];
#pragma unroll
  for (int mi = 0; mi < 4; ++mi)
#pragma unroll
    for (int ni = 0; ni < 4; ++ni) acc[mi][ni] = fz;

  const bf16* Abase = A + (size_t)m0 * K;
  const bf16* Wbase = W + (size_t)n0 * K;
  const int c0 = tid, c1 = 256 + tid;   // 16B chunk ids; chunk c: row=c>>2, colchunk=c&3

  for (int k0 = 0; k0 < K; k0 += BK) {
    __syncthreads();
    gload_lds16(Abase + (size_t)(c0 >> 2) * K + k0 + (c0 & 3) * 8, As + c0 * 8);
    gload_lds16(Abase + (size_t)(c1 >> 2) * K + k0 + (c1 & 3) * 8, As + c1 * 8);
    gload_lds16(Wbase + (size_t)(c0 >> 2) * K + k0 + (c0 & 3) * 8, Bs + c0 * 8);
    gload_lds16(Wbase + (size_t)(c1 >> 2) * K + k0 + (c1 & 3) * 8, Bs + c1 * 8);
    __syncthreads();

    bf16x8 af[4], bfr[4];
#pragma unroll
    for (int mi = 0; mi < 4; ++mi)
      af[mi] = *reinterpret_cast<const bf16x8*>(As + (wr * 64 + mi * 16 + r16) * BK + 8 * g);
#pragma unroll
    for (int ni = 0; ni < 4; ++ni)
      bfr[ni] = *reinterpret_cast<const bf16x8*>(Bs + (wc * 64 + ni * 16 + r16) * BK + 8 * g);
#pragma unroll
    for (int mi = 0; mi < 4; ++mi)
#pragma unroll
      for (int ni = 0; ni < 4; ++ni)
        acc[mi][ni] = __builtin_amdgcn_mfma_f32_16x16x32_bf16(af[mi], bfr[ni], acc[mi][ni], 0, 0, 0);
  }

  // epilogue: bias (+ RoPE) (+ scatter)
#pragma unroll
  for (int mi = 0; mi < 4; ++mi) {
#pragma unroll
    for (int ni = 0; ni < 4; ++ni) {
      const int gn = n0 + wc * 64 + ni * 16 + r16;
      const float bv = bias[gn];
#pragma unroll
      for (int r = 0; r < 4; ++r) {
        const int gm = m0 + wr * 64 + mi * 16 + g * 4 + r;
        float val = acc[mi][ni][r] + bv;
        if (ROPE) {
          const int srow = gm & (S_ - 1);
          const int d = gn & 63;
          const float cs = costab[srow * 32 + (d >> 1)];
          const float sn = sintab[srow * 32 + (d >> 1)];
          const float pv = __shfl_xor(val, 1);   // partner column (gn^1), same (mi,ni,r)
          val = (d & 1) ? (val * cs + pv * sn) : (val * cs - pv * sn);
        }
        if (SCATTER) {
          const int b = gm >> 11, srow = gm & (S_ - 1);
          const int h = gn >> 6, d = gn & 63;
          outS[(((size_t)(b * H_ + h)) * S_ + srow) * D_ + d] = __float2bfloat16(val);
        } else {
          outF[(size_t)gm * 1024 + gn] = val;
        }
      }
    }
  }
}

// ---------------- causal flash attention ----------------
// Q,K,V: [B*H][S][64] bf16.  Out: attnO [b][s][h*64+d] bf16.
// Block: 64 q rows, 4 waves x 16 rows. KV tile = 32.
__global__ __launch_bounds__(256)
void attn_kernel(const bf16* __restrict__ Q, const bf16* __restrict__ Kg,
                 const bf16* __restrict__ V, bf16* __restrict__ Og)
{
  __shared__ __align__(16) bf16 Ks[32 * 64];     // xor-swizzled by 16B chunk within row
  __shared__ __align__(16) bf16 Vt[64][40];      // V^T, padded (row stride 80B)
  __shared__ __align__(16) bf16 Pl[4][16][40];   // per-wave P staging, padded
  const int bh = blockIdx.y;
  const int q0 = blockIdx.x * 64;
  const int tid = threadIdx.x, lane = tid & 63, wid = tid >> 6;
  const int g = lane >> 4, r16 = lane & 15;
  const size_t base = (size_t)bh * S_ * D_;
  const bf16* Qb = Q + base;
  const bf16* Kb = Kg + base;
  const bf16* Vb = V + base;
  const int b = bh >> 4, h = bh & 15;
  bf16* Ob = Og + (size_t)b * S_ * E_ + h * D_;

  const int qw0 = q0 + wid * 16;
  const bf16x8 qf0 = *reinterpret_cast<const bf16x8*>(Qb + (size_t)(qw0 + r16) * 64 + 8 * g);
  const bf16x8 qf1 = *reinterpret_cast<const bf16x8*>(Qb + (size_t)(qw0 + r16) * 64 + 32 + 8 * g);

  const f32x4 fz = {0.f, 0.f, 0.f, 0.f};
  f32x4 oacc[4];
#pragma unroll
  for (int dt = 0; dt < 4; ++dt) oacc[dt] = fz;
  float mrow[4], lrow[4];
#pragma unroll
  for (int r = 0; r < 4; ++r) { mrow[r] = -__builtin_inff(); lrow[r] = 0.f; }

  const int nkt = (q0 >> 5) + 2;
  const int stg_row = tid >> 3, stg_c = tid & 7;   // 32 rows x 8 chunks of 16B

  for (int kt = 0; kt < nkt; ++kt) {
    const int k0 = kt * 32;
    __syncthreads();
    // K tile: linear LDS dest, xor-swizzled global source (chunk ^ (row&7))
    gload_lds16(Kb + (size_t)(k0 + stg_row) * 64 + ((stg_c ^ (stg_row & 7)) * 8), &Ks[tid * 8]);
    // V tile transposed into padded LDS
    {
      union { bf16x8 v; bf16 e[8]; } u;
      u.v = *reinterpret_cast<const bf16x8*>(Vb + (size_t)(k0 + stg_row) * 64 + stg_c * 8);
#pragma unroll
      for (int j = 0; j < 8; ++j) Vt[stg_c * 8 + j][stg_row] = u.e[j];
    }
    __syncthreads();

    // QK^T: S[q][k], q rows of this wave, k = k0..k0+31
    float ps[2][4];
#pragma unroll
    for (int kc = 0; kc < 2; ++kc) {
      const int krow = kc * 16 + r16;
      const int sw = krow & 7;
      const bf16x8 kf0 = *reinterpret_cast<const bf16x8*>(&Ks[krow * 64 + ((g ^ sw) * 8)]);
      const bf16x8 kf1 = *reinterpret_cast<const bf16x8*>(&Ks[krow * 64 + (((g + 4) ^ sw) * 8)]);
      f32x4 sacc = fz;
      sacc = __builtin_amdgcn_mfma_f32_16x16x32_bf16(qf0, kf0, sacc, 0, 0, 0);
      sacc = __builtin_amdgcn_mfma_f32_16x16x32_bf16(qf1, kf1, sacc, 0, 0, 0);
#pragma unroll
      for (int r = 0; r < 4; ++r) ps[kc][r] = sacc[r] * SCALE_;
    }
    // causal mask (only needed when tile overlaps diagonal of this wave)
    if (k0 + 31 > qw0) {
#pragma unroll
      for (int kc = 0; kc < 2; ++kc)
#pragma unroll
        for (int r = 0; r < 4; ++r) {
          const int kcol = k0 + kc * 16 + r16;
          const int qrow = qw0 + g * 4 + r;
          if (kcol > qrow) ps[kc][r] = -1e30f;
        }
    }
    // online softmax; row lives across the 16 lanes of this lane-group
    float mn[4], scl[4];
#pragma unroll
    for (int r = 0; r < 4; ++r) {
      float v = fmaxf(ps[0][r], ps[1][r]);
      v = fmaxf(v, __shfl_xor(v, 1));
      v = fmaxf(v, __shfl_xor(v, 2));
      v = fmaxf(v, __shfl_xor(v, 4));
      v = fmaxf(v, __shfl_xor(v, 8));
      mn[r] = fmaxf(mrow[r], v);
      scl[r] = __expf(mrow[r] - mn[r]);
      mrow[r] = mn[r];
    }
#pragma unroll
    for (int r = 0; r < 4; ++r) {
      float p0 = __expf(ps[0][r] - mn[r]);
      float p1 = __expf(ps[1][r] - mn[r]);
      ps[0][r] = p0; ps[1][r] = p1;
      float s = p0 + p1;
      s += __shfl_xor(s, 1);
      s += __shfl_xor(s, 2);
      s += __shfl_xor(s, 4);
      s += __shfl_xor(s, 8);
      lrow[r] = lrow[r] * scl[r] + s;
    }
#pragma unroll
    for (int dt = 0; dt < 4; ++dt)
#pragma unroll
      for (int r = 0; r < 4; ++r) oacc[dt][r] *= scl[r];
    // stage P (D-layout) -> LDS -> re-read in A-fragment layout (wave-local sync)
#pragma unroll
    for (int kc = 0; kc < 2; ++kc)
#pragma unroll
      for (int r = 0; r < 4; ++r)
        Pl[wid][g * 4 + r][kc * 16 + r16] = __float2bfloat16(ps[kc][r]);
    asm volatile("s_waitcnt lgkmcnt(0)" ::: "memory");
    const bf16x8 pa = *reinterpret_cast<const bf16x8*>(&Pl[wid][r16][8 * g]);
#pragma unroll
    for (int dt = 0; dt < 4; ++dt) {
      const bf16x8 vf = *reinterpret_cast<const bf16x8*>(&Vt[dt * 16 + r16][8 * g]);
      oacc[dt] = __builtin_amdgcn_mfma_f32_16x16x32_bf16(pa, vf, oacc[dt], 0, 0, 0);
    }
  }

  // normalize and store to [b][s][h*64+d]
#pragma unroll
  for (int dt = 0; dt < 4; ++dt)
#pragma unroll
    for (int r = 0; r < 4; ++r) {
      const int qrow = qw0 + g * 4 + r;
      const float ov = oacc[dt][r] / lrow[r];
      Ob[(size_t)qrow * E_ + dt * 16 + r16] = __float2bfloat16(ov);
    }
}

extern "C" void kernel_launch(void* const* d_in, const int* in_sizes, int n_in,
                              void* d_out, int out_size, void* d_ws, size_t ws_size,
                              hipStream_t stream) {
  const float* x  = (const float*)d_in[0];
  const float* Wq = (const float*)d_in[1];
  const float* bq = (const float*)d_in[2];
  const float* Wk = (const float*)d_in[3];
  const float* bk = (const float*)d_in[4];
  const float* Wv = (const float*)d_in[5];
  const float* bv = (const float*)d_in[6];
  const float* Wo = (const float*)d_in[7];
  const float* bo = (const float*)d_in[8];
  float* out = (float*)d_out;

  char* ws = (char*)d_ws;
  size_t off = 0;
  auto alloc = [&](size_t bytes) -> char* {
    char* p = ws + off; off += (bytes + 255) & ~(size_t)255; return p;
  };
  bf16* xb   = (bf16*)alloc((size_t)M_ * E_ * 2);
  bf16* Wqb  = (bf16*)alloc((size_t)E_ * E_ * 2);
  bf16* Wkb  = (bf16*)alloc((size_t)E_ * E_ * 2);
  bf16* Wvb  = (bf16*)alloc((size_t)E_ * E_ * 2);
  bf16* Wob  = (bf16*)alloc((size_t)E_ * E_ * 2);
  bf16* Qb   = (bf16*)alloc((size_t)M_ * E_ * 2);   // [b][h][s][d]
  bf16* Kb   = (bf16*)alloc((size_t)M_ * E_ * 2);
  bf16* Vb   = (bf16*)alloc((size_t)M_ * E_ * 2);
  bf16* AOb  = (bf16*)alloc((size_t)M_ * E_ * 2);   // [b][s][e]
  float* sintab = (float*)alloc((size_t)S_ * 32 * 4);
  float* costab = (float*)alloc((size_t)S_ * 32 * 4);

  cast_kernel<<<M_ * E_ / 4 / 256, 256, 0, stream>>>(x,  xb,  M_ * E_ / 4);
  cast_kernel<<<E_ * E_ / 4 / 256, 256, 0, stream>>>(Wq, Wqb, E_ * E_ / 4);
  cast_kernel<<<E_ * E_ / 4 / 256, 256, 0, stream>>>(Wk, Wkb, E_ * E_ / 4);
  cast_kernel<<<E_ * E_ / 4 / 256, 256, 0, stream>>>(Wv, Wvb, E_ * E_ / 4);
  cast_kernel<<<E_ * E_ / 4 / 256, 256, 0, stream>>>(Wo, Wob, E_ * E_ / 4);
  rope_table_kernel<<<S_ * 32 / 256, 256, 0, stream>>>(sintab, costab);

  dim3 gg(8, 32), bb(256);
  gemm_kernel<true,  true ><<<gg, bb, 0, stream>>>(xb, Wqb, bq, Qb, nullptr, sintab, costab);
  gemm_kernel<true,  true ><<<gg, bb, 0, stream>>>(xb, Wkb, bk, Kb, nullptr, sintab, costab);
  gemm_kernel<false, true ><<<gg, bb, 0, stream>>>(xb, Wvb, bv, Vb, nullptr, nullptr, nullptr);

  attn_kernel<<<dim3(S_ / 64, B_ * H_), 256, 0, stream>>>(Qb, Kb, Vb, AOb);

  gemm_kernel<false, false><<<gg, bb, 0, stream>>>(AOb, Wob, bo, nullptr, out, nullptr, nullptr);
}

// Round 2
// 219.031 us; speedup vs baseline: 1.5036x; 1.5036x over previous
//
#include <hip/hip_runtime.h>
#include <hip/hip_bf16.h>
#include <cstdint>
#include <cstddef>

typedef __hip_bfloat16 bf16;
typedef __attribute__((ext_vector_type(8))) short bf16x8;
typedef __attribute__((ext_vector_type(4))) float f32x4;

#define AS1C(p) ((const __attribute__((address_space(1))) void*)(p))
#define AS3(p)  ((__attribute__((address_space(3))) void*)(p))

constexpr int B_ = 2, S_ = 2048, E_ = 1024, H_ = 16, D_ = 64;
constexpr int M_ = B_ * S_;                      // 4096
constexpr float QSCALE_ = 0.125f * 1.44269504088896340736f;  // 1/sqrt(64) * log2(e)

__device__ __forceinline__ void gload_lds16(const bf16* g, bf16* l) {
  __builtin_amdgcn_global_load_lds(AS1C(g), AS3(l), 16, 0, 0);
}

// ---------------- cast f32 -> bf16, 4 elems/thread ----------------
__global__ void cast_kernel(const float* __restrict__ in, bf16* __restrict__ out, int n4) {
  int i = blockIdx.x * blockDim.x + threadIdx.x;
  if (i >= n4) return;
  float4 v = reinterpret_cast<const float4*>(in)[i];
  union { bf16 b[4]; short4 s; } u;
  u.b[0] = __float2bfloat16(v.x);
  u.b[1] = __float2bfloat16(v.y);
  u.b[2] = __float2bfloat16(v.z);
  u.b[3] = __float2bfloat16(v.w);
  reinterpret_cast<short4*>(out)[i] = u.s;
}

// ---------------- cast Wq|Wk|Wv into one buffer + concat biases ----------------
__global__ void cast3_kernel(const float* __restrict__ Wq, const float* __restrict__ Wk,
                             const float* __restrict__ Wv,
                             const float* __restrict__ bq, const float* __restrict__ bk,
                             const float* __restrict__ bv,
                             bf16* __restrict__ Wqkv, float* __restrict__ bqkv) {
  const int i = blockIdx.x * 256 + threadIdx.x;
  const int wn4 = 3 * E_ * E_ / 4;               // 786432
  if (i < wn4) {
    const int which = i >> 18;                   // E_*E_/4 = 2^18
    const int j = i & ((1 << 18) - 1);
    const float* src = which == 0 ? Wq : (which == 1 ? Wk : Wv);
    float4 v = reinterpret_cast<const float4*>(src)[j];
    union { bf16 b[4]; short4 s; } u;
    u.b[0] = __float2bfloat16(v.x);
    u.b[1] = __float2bfloat16(v.y);
    u.b[2] = __float2bfloat16(v.z);
    u.b[3] = __float2bfloat16(v.w);
    reinterpret_cast<short4*>(Wqkv)[i] = u.s;
  } else {
    const int j = i - wn4;
    if (j < 768) {
      const int which = j >> 8;
      const int jj = j & 255;
      const float* src = which == 0 ? bq : (which == 1 ? bk : bv);
      reinterpret_cast<float4*>(bqkv)[j] = reinterpret_cast<const float4*>(src)[jj];
    }
  }
}

// ---------------- RoPE sin/cos tables: [S][32] ----------------
__global__ void rope_table_kernel(float* __restrict__ sintab, float* __restrict__ costab) {
  int idx = blockIdx.x * blockDim.x + threadIdx.x;
  int s = idx >> 5, i = idx & 31;
  float inv = powf(10000.0f, -(float)i / 32.0f);
  float ang = (float)s * inv;
  sintab[idx] = sinf(ang);
  costab[idx] = cosf(ang);
}

// ---------------- GEMM: C = A(M x 1024) * W^T (W is N x K) + bias ----------------
// MODE 0: fused QKV (N=3072): rope on q/k, scale q by QSCALE_, scatter bf16 to [b][h][s][d]
// MODE 1: final O-proj (N=1024): write f32 [m][n]
template<int MODE>
__global__ __launch_bounds__(256)
void gemm_kernel(const bf16* __restrict__ A, const bf16* __restrict__ W,
                 const float* __restrict__ bias,
                 bf16* __restrict__ Qo, bf16* __restrict__ Ko, bf16* __restrict__ Vo,
                 float* __restrict__ outF,
                 const float* __restrict__ sintab, const float* __restrict__ costab)
{
  constexpr int K = 1024, BK = 32;
  __shared__ __align__(16) bf16 As[128 * BK];
  __shared__ __align__(16) bf16 Bs[128 * BK];
  const int tid = threadIdx.x;
  const int lane = tid & 63, wid = tid >> 6;
  const int g = lane >> 4, r16 = lane & 15;
  const int wr = wid >> 1, wc = wid & 1;
  const int m0 = blockIdx.y * 128, n0 = blockIdx.x * 128;

  const f32x4 fz = {0.f, 0.f, 0.f, 0.f};
  f32x4 acc[4][4];
#pragma unroll
  for (int mi = 0; mi < 4; ++mi)
#pragma unroll
    for (int ni = 0; ni < 4; ++ni) acc[mi][ni] = fz;

  const bf16* Abase = A + (size_t)m0 * K;
  const bf16* Wbase = W + (size_t)n0 * K;
  const int c0 = tid, c1 = 256 + tid;

  for (int k0 = 0; k0 < K; k0 += BK) {
    __syncthreads();
    gload_lds16(Abase + (size_t)(c0 >> 2) * K + k0 + (c0 & 3) * 8, As + c0 * 8);
    gload_lds16(Abase + (size_t)(c1 >> 2) * K + k0 + (c1 & 3) * 8, As + c1 * 8);
    gload_lds16(Wbase + (size_t)(c0 >> 2) * K + k0 + (c0 & 3) * 8, Bs + c0 * 8);
    gload_lds16(Wbase + (size_t)(c1 >> 2) * K + k0 + (c1 & 3) * 8, Bs + c1 * 8);
    __syncthreads();

    bf16x8 af[4], bfr[4];
#pragma unroll
    for (int mi = 0; mi < 4; ++mi)
      af[mi] = *reinterpret_cast<const bf16x8*>(As + (wr * 64 + mi * 16 + r16) * BK + 8 * g);
#pragma unroll
    for (int ni = 0; ni < 4; ++ni)
      bfr[ni] = *reinterpret_cast<const bf16x8*>(Bs + (wc * 64 + ni * 16 + r16) * BK + 8 * g);
#pragma unroll
    for (int mi = 0; mi < 4; ++mi)
#pragma unroll
      for (int ni = 0; ni < 4; ++ni)
        acc[mi][ni] = __builtin_amdgcn_mfma_f32_16x16x32_bf16(af[mi], bfr[ni], acc[mi][ni], 0, 0, 0);
  }

#pragma unroll
  for (int mi = 0; mi < 4; ++mi) {
#pragma unroll
    for (int ni = 0; ni < 4; ++ni) {
      const int gn = n0 + wc * 64 + ni * 16 + r16;
      const float bv = bias[gn];
#pragma unroll
      for (int r = 0; r < 4; ++r) {
        const int gm = m0 + wr * 64 + mi * 16 + g * 4 + r;
        float val = acc[mi][ni][r] + bv;
        if (MODE == 0) {
          const int which = gn >> 10;
          const int d = gn & 63;
          const int srow = gm & (S_ - 1);
          if (which < 2) {
            const float cs = costab[srow * 32 + (d >> 1)];
            const float sn = sintab[srow * 32 + (d >> 1)];
            const float pv = __shfl_xor(val, 1);
            val = (d & 1) ? (val * cs + pv * sn) : (val * cs - pv * sn);
          }
          if (which == 0) val *= QSCALE_;
          const int b = gm >> 11;
          const int h = (gn >> 6) & 15;
          bf16* dst = which == 0 ? Qo : (which == 1 ? Ko : Vo);
          dst[(((size_t)(b * H_ + h)) * S_ + srow) * D_ + d] = __float2bfloat16(val);
        } else {
          outF[(size_t)gm * 1024 + gn] = val;
        }
      }
    }
  }
}

// ---------------- causal flash attention v2 ----------------
// Q pre-scaled by 1/sqrt(d)*log2e. Q,K,V: [B*H][S][64] bf16. Out: [b][s][h*64+d] bf16.
// Block: 128 q rows, 4 waves x 32 rows. KV tile = 64. Heavy blocks dispatched first.
__global__ __launch_bounds__(256)
void attn_kernel(const bf16* __restrict__ Q, const bf16* __restrict__ Kg,
                 const bf16* __restrict__ V, bf16* __restrict__ Og)
{
  __shared__ __align__(16) bf16 Ks[64 * 64];       // linear rows, 16B-chunk-xor-swizzled source
  __shared__ __align__(16) bf16 Vt[64 * 72];       // V^T: (d,k) at d*72 + ((k>>3)^((d>>3)&7))*8 + (k&7)
  __shared__ __align__(16) bf16 Pl[4][16][72];     // per-wave P staging
  const int bh = blockIdx.y;
  const int qblk = (gridDim.x - 1) - blockIdx.x;   // heavy-first
  const int q0 = qblk * 128;
  const int tid = threadIdx.x, lane = tid & 63, wid = tid >> 6;
  const int g = lane >> 4, r16 = lane & 15;
  const size_t base = (size_t)bh * S_ * D_;
  const bf16* Qb = Q + base;
  const bf16* Kb = Kg + base;
  const bf16* Vb = V + base;
  const int b = bh >> 4, h = bh & 15;
  bf16* Ob = Og + (size_t)b * S_ * E_ + h * D_;
  const int qw0 = q0 + wid * 32;

  bf16x8 qf[2][2];
#pragma unroll
  for (int mi = 0; mi < 2; ++mi)
#pragma unroll
    for (int hh = 0; hh < 2; ++hh)
      qf[mi][hh] = *reinterpret_cast<const bf16x8*>(Qb + (size_t)(qw0 + mi * 16 + r16) * 64 + hh * 32 + 8 * g);

  const f32x4 fz = {0.f, 0.f, 0.f, 0.f};
  f32x4 oacc[2][4];
#pragma unroll
  for (int mi = 0; mi < 2; ++mi)
#pragma unroll
    for (int dt = 0; dt < 4; ++dt) oacc[mi][dt] = fz;
  float mrow[2][4], lrow[2][4];
#pragma unroll
  for (int mi = 0; mi < 2; ++mi)
#pragma unroll
    for (int r = 0; r < 4; ++r) { mrow[mi][r] = -__builtin_inff(); lrow[mi][r] = 0.f; }

  const int nkt = 2 * qblk + 2;
  const int vrow = tid >> 3, vc = tid & 7;         // 32 rows x 8 chunks per half-tile
  const int kc0 = tid, kc1 = 256 + tid;            // K: 512 16B-chunks

  for (int kt = 0; kt < nkt; ++kt) {
    const int k0 = kt * 64;
    // V tile -> regs (global loads; drained at the next barrier)
    union { bf16x8 v; bf16 e[8]; } u0, u1;
    u0.v = *reinterpret_cast<const bf16x8*>(Vb + (size_t)(k0 + vrow) * 64 + vc * 8);
    u1.v = *reinterpret_cast<const bf16x8*>(Vb + (size_t)(k0 + 32 + vrow) * 64 + vc * 8);
    __syncthreads();
    // K tile: linear LDS dest, xor-swizzled global source
    {
      const int r0 = kc0 >> 3, cc0 = kc0 & 7;
      gload_lds16(Kb + (size_t)(k0 + r0) * 64 + ((cc0 ^ (r0 & 7)) * 8), Ks + kc0 * 8);
      const int r1 = kc1 >> 3, cc1 = kc1 & 7;
      gload_lds16(Kb + (size_t)(k0 + r1) * 64 + ((cc1 ^ (r1 & 7)) * 8), Ks + kc1 * 8);
    }
    // V transpose into swizzled Vt
    {
      const int sw0 = (vrow >> 3) ^ vc;
      const int sw1 = ((32 + vrow) >> 3) ^ vc;
#pragma unroll
      for (int j = 0; j < 8; ++j)
        Vt[(vc * 8 + j) * 72 + sw0 * 8 + (vrow & 7)] = u0.e[j];
#pragma unroll
      for (int j = 0; j < 8; ++j)
        Vt[(vc * 8 + j) * 72 + sw1 * 8 + (vrow & 7)] = u1.e[j];
    }
    __syncthreads();

    if (k0 <= qw0 + 31) {                          // whole tile masked for this wave? skip compute
      // ---- QK^T ----
      bf16x8 kfr[4][2];
      const int sw = r16 & 7;
#pragma unroll
      for (int kf = 0; kf < 4; ++kf) {
        const int krow = kf * 16 + r16;
        kfr[kf][0] = *reinterpret_cast<const bf16x8*>(&Ks[krow * 64 + ((g ^ sw) * 8)]);
        kfr[kf][1] = *reinterpret_cast<const bf16x8*>(&Ks[krow * 64 + (((g + 4) ^ sw) * 8)]);
      }
      f32x4 ps[2][4];
#pragma unroll
      for (int mi = 0; mi < 2; ++mi)
#pragma unroll
        for (int kf = 0; kf < 4; ++kf) {
          f32x4 sa = fz;
          sa = __builtin_amdgcn_mfma_f32_16x16x32_bf16(qf[mi][0], kfr[kf][0], sa, 0, 0, 0);
          sa = __builtin_amdgcn_mfma_f32_16x16x32_bf16(qf[mi][1], kfr[kf][1], sa, 0, 0, 0);
          ps[mi][kf] = sa;
        }
      // ---- causal mask ----
      if (k0 + 63 > qw0) {
#pragma unroll
        for (int mi = 0; mi < 2; ++mi)
#pragma unroll
          for (int kf = 0; kf < 4; ++kf)
#pragma unroll
            for (int r = 0; r < 4; ++r) {
              const int qrow = qw0 + mi * 16 + g * 4 + r;
              const int kcol = k0 + kf * 16 + r16;
              if (kcol > qrow) ps[mi][kf][r] = -1e30f;
            }
      }
      // ---- online softmax (base-2 domain; Q pre-scaled by log2e/sqrt(d)) ----
#pragma unroll
      for (int mi = 0; mi < 2; ++mi) {
        float mn[4], scl[4];
#pragma unroll
        for (int r = 0; r < 4; ++r) {
          float v = fmaxf(fmaxf(ps[mi][0][r], ps[mi][1][r]), fmaxf(ps[mi][2][r], ps[mi][3][r]));
          v = fmaxf(v, __shfl_xor(v, 1));
          v = fmaxf(v, __shfl_xor(v, 2));
          v = fmaxf(v, __shfl_xor(v, 4));
          v = fmaxf(v, __shfl_xor(v, 8));
          mn[r] = fmaxf(mrow[mi][r], v);
          scl[r] = exp2f(mrow[mi][r] - mn[r]);
          mrow[mi][r] = mn[r];
        }
#pragma unroll
        for (int r = 0; r < 4; ++r) {
          float s = 0.f;
#pragma unroll
          for (int kf = 0; kf < 4; ++kf) {
            float p = exp2f(ps[mi][kf][r] - mn[r]);
            ps[mi][kf][r] = p;
            s += p;
          }
          s += __shfl_xor(s, 1);
          s += __shfl_xor(s, 2);
          s += __shfl_xor(s, 4);
          s += __shfl_xor(s, 8);
          lrow[mi][r] = lrow[mi][r] * scl[r] + s;
        }
#pragma unroll
        for (int dt = 0; dt < 4; ++dt)
#pragma unroll
          for (int r = 0; r < 4; ++r) oacc[mi][dt][r] *= scl[r];
        // ---- P -> LDS (D-layout) -> A-fragment layout ----
#pragma unroll
        for (int kf = 0; kf < 4; ++kf)
#pragma unroll
          for (int r = 0; r < 4; ++r)
            Pl[wid][g * 4 + r][kf * 16 + r16] = __float2bfloat16(ps[mi][kf][r]);
#pragma unroll
        for (int ks = 0; ks < 2; ++ks) {
          const bf16x8 pa = *reinterpret_cast<const bf16x8*>(&Pl[wid][r16][ks * 32 + g * 8]);
#pragma unroll
          for (int dt = 0; dt < 4; ++dt) {
            const int d = dt * 16 + r16;
            const bf16x8 vf = *reinterpret_cast<const bf16x8*>(
                &Vt[d * 72 + (((ks * 4 + g) ^ ((d >> 3) & 7)) * 8)]);
            oacc[mi][dt] = __builtin_amdgcn_mfma_f32_16x16x32_bf16(pa, vf, oacc[mi][dt], 0, 0, 0);
          }
        }
      }
    }
  }

  // ---- normalize + store ----
#pragma unroll
  for (int mi = 0; mi < 2; ++mi)
#pragma unroll
    for (int dt = 0; dt < 4; ++dt)
#pragma unroll
      for (int r = 0; r < 4; ++r) {
        const int qrow = qw0 + mi * 16 + g * 4 + r;
        const float ov = oacc[mi][dt][r] / lrow[mi][r];
        Ob[(size_t)qrow * E_ + dt * 16 + r16] = __float2bfloat16(ov);
      }
}

extern "C" void kernel_launch(void* const* d_in, const int* in_sizes, int n_in,
                              void* d_out, int out_size, void* d_ws, size_t ws_size,
                              hipStream_t stream) {
  const float* x  = (const float*)d_in[0];
  const float* Wq = (const float*)d_in[1];
  const float* bq = (const float*)d_in[2];
  const float* Wk = (const float*)d_in[3];
  const float* bk = (const float*)d_in[4];
  const float* Wv = (const float*)d_in[5];
  const float* bv = (const float*)d_in[6];
  const float* Wo = (const float*)d_in[7];
  const float* bo = (const float*)d_in[8];
  float* out = (float*)d_out;

  char* ws = (char*)d_ws;
  size_t off = 0;
  auto alloc = [&](size_t bytes) -> char* {
    char* p = ws + off; off += (bytes + 255) & ~(size_t)255; return p;
  };
  bf16* xb    = (bf16*)alloc((size_t)M_ * E_ * 2);
  bf16* Wqkvb = (bf16*)alloc((size_t)3 * E_ * E_ * 2);
  bf16* Wob   = (bf16*)alloc((size_t)E_ * E_ * 2);
  float* bqkv = (float*)alloc((size_t)3 * E_ * 4);
  bf16* Qb    = (bf16*)alloc((size_t)M_ * E_ * 2);   // [b][h][s][d]
  bf16* Kb    = (bf16*)alloc((size_t)M_ * E_ * 2);
  bf16* Vb    = (bf16*)alloc((size_t)M_ * E_ * 2);
  bf16* AOb   = (bf16*)alloc((size_t)M_ * E_ * 2);   // [b][s][e]
  float* sintab = (float*)alloc((size_t)S_ * 32 * 4);
  float* costab = (float*)alloc((size_t)S_ * 32 * 4);

  cast_kernel<<<M_ * E_ / 4 / 256, 256, 0, stream>>>(x, xb, M_ * E_ / 4);
  cast_kernel<<<E_ * E_ / 4 / 256, 256, 0, stream>>>(Wo, Wob, E_ * E_ / 4);
  cast3_kernel<<<(3 * E_ * E_ / 4 + 768 + 255) / 256, 256, 0, stream>>>(
      Wq, Wk, Wv, bq, bk, bv, Wqkvb, bqkv);
  rope_table_kernel<<<S_ * 32 / 256, 256, 0, stream>>>(sintab, costab);

  gemm_kernel<0><<<dim3(24, 32), 256, 0, stream>>>(xb, Wqkvb, bqkv, Qb, Kb, Vb,
                                                   nullptr, sintab, costab);
  attn_kernel<<<dim3(16, 32), 256, 0, stream>>>(Qb, Kb, Vb, AOb);
  gemm_kernel<1><<<dim3(8, 32), 256, 0, stream>>>(AOb, Wob, bo, nullptr, nullptr, nullptr,
                                                  out, nullptr, nullptr);
}

// Round 3
// 192.638 us; speedup vs baseline: 1.7096x; 1.1370x over previous
//
#include <hip/hip_runtime.h>
#include <hip/hip_bf16.h>
#include <cstdint>
#include <cstddef>

typedef __hip_bfloat16 bf16;
typedef __attribute__((ext_vector_type(8))) short bf16x8;
typedef __attribute__((ext_vector_type(4))) float f32x4;

#define AS1C(p) ((const __attribute__((address_space(1))) void*)(p))
#define AS3(p)  ((__attribute__((address_space(3))) void*)(p))

constexpr int B_ = 2, S_ = 2048, E_ = 1024, H_ = 16, D_ = 64;
constexpr int M_ = B_ * S_;                      // 4096
constexpr float QSCALE_ = 0.125f * 1.44269504088896340736f;  // 1/sqrt(64) * log2(e)

__device__ __forceinline__ void gload_lds16(const bf16* g, bf16* l) {
  __builtin_amdgcn_global_load_lds(AS1C(g), AS3(l), 16, 0, 0);
}

// ---------------- cast f32 -> bf16, 4 elems/thread ----------------
__global__ void cast_kernel(const float* __restrict__ in, bf16* __restrict__ out, int n4) {
  int i = blockIdx.x * blockDim.x + threadIdx.x;
  if (i >= n4) return;
  float4 v = reinterpret_cast<const float4*>(in)[i];
  union { bf16 b[4]; short4 s; } u;
  u.b[0] = __float2bfloat16(v.x);
  u.b[1] = __float2bfloat16(v.y);
  u.b[2] = __float2bfloat16(v.z);
  u.b[3] = __float2bfloat16(v.w);
  reinterpret_cast<short4*>(out)[i] = u.s;
}

// ---------------- cast Wq|Wk|Wv into one buffer + concat biases ----------------
__global__ void cast3_kernel(const float* __restrict__ Wq, const float* __restrict__ Wk,
                             const float* __restrict__ Wv,
                             const float* __restrict__ bq, const float* __restrict__ bk,
                             const float* __restrict__ bv,
                             bf16* __restrict__ Wqkv, float* __restrict__ bqkv) {
  const int i = blockIdx.x * 256 + threadIdx.x;
  const int wn4 = 3 * E_ * E_ / 4;               // 786432
  if (i < wn4) {
    const int which = i >> 18;                   // E_*E_/4 = 2^18
    const int j = i & ((1 << 18) - 1);
    const float* src = which == 0 ? Wq : (which == 1 ? Wk : Wv);
    float4 v = reinterpret_cast<const float4*>(src)[j];
    union { bf16 b[4]; short4 s; } u;
    u.b[0] = __float2bfloat16(v.x);
    u.b[1] = __float2bfloat16(v.y);
    u.b[2] = __float2bfloat16(v.z);
    u.b[3] = __float2bfloat16(v.w);
    reinterpret_cast<short4*>(Wqkv)[i] = u.s;
  } else {
    const int j = i - wn4;
    if (j < 768) {
      const int which = j >> 8;
      const int jj = j & 255;
      const float* src = which == 0 ? bq : (which == 1 ? bk : bv);
      reinterpret_cast<float4*>(bqkv)[j] = reinterpret_cast<const float4*>(src)[jj];
    }
  }
}

// ---------------- RoPE sin/cos tables: [S][32] ----------------
__global__ void rope_table_kernel(float* __restrict__ sintab, float* __restrict__ costab) {
  int idx = blockIdx.x * blockDim.x + threadIdx.x;
  int s = idx >> 5, i = idx & 31;
  float inv = powf(10000.0f, -(float)i / 32.0f);
  float ang = (float)s * inv;
  sintab[idx] = sinf(ang);
  costab[idx] = cosf(ang);
}

// ---------------- GEMM: C = A(M x 1024) * W^T (W is N x K) + bias ----------------
// MODE 0: fused QKV (N=3072): rope on q/k, scale q by QSCALE_, scatter bf16 to [b][h][s][d]
// MODE 1: final O-proj (N=1024): write f32 [m][n]
template<int MODE>
__global__ __launch_bounds__(256)
void gemm_kernel(const bf16* __restrict__ A, const bf16* __restrict__ W,
                 const float* __restrict__ bias,
                 bf16* __restrict__ Qo, bf16* __restrict__ Ko, bf16* __restrict__ Vo,
                 float* __restrict__ outF,
                 const float* __restrict__ sintab, const float* __restrict__ costab)
{
  constexpr int K = 1024, BK = 32;
  __shared__ __align__(16) bf16 As[128 * BK];
  __shared__ __align__(16) bf16 Bs[128 * BK];
  const int tid = threadIdx.x;
  const int lane = tid & 63, wid = tid >> 6;
  const int g = lane >> 4, r16 = lane & 15;
  const int wr = wid >> 1, wc = wid & 1;

  // bijective XCD swizzle: XCD j processes a contiguous logical-tile range
  const int nwg = gridDim.x * gridDim.y;           // divisible by 8
  const int flat = blockIdx.y * gridDim.x + blockIdx.x;
  const int cpx = nwg >> 3;
  const int f2 = (flat & 7) * cpx + (flat >> 3);
  const int m0 = (f2 / gridDim.x) * 128, n0 = (f2 % gridDim.x) * 128;

  const f32x4 fz = {0.f, 0.f, 0.f, 0.f};
  f32x4 acc[4][4];
#pragma unroll
  for (int mi = 0; mi < 4; ++mi)
#pragma unroll
    for (int ni = 0; ni < 4; ++ni) acc[mi][ni] = fz;

  const bf16* Abase = A + (size_t)m0 * K;
  const bf16* Wbase = W + (size_t)n0 * K;
  const int c0 = tid, c1 = 256 + tid;

  for (int k0 = 0; k0 < K; k0 += BK) {
    __syncthreads();
    gload_lds16(Abase + (size_t)(c0 >> 2) * K + k0 + (c0 & 3) * 8, As + c0 * 8);
    gload_lds16(Abase + (size_t)(c1 >> 2) * K + k0 + (c1 & 3) * 8, As + c1 * 8);
    gload_lds16(Wbase + (size_t)(c0 >> 2) * K + k0 + (c0 & 3) * 8, Bs + c0 * 8);
    gload_lds16(Wbase + (size_t)(c1 >> 2) * K + k0 + (c1 & 3) * 8, Bs + c1 * 8);
    __syncthreads();

    bf16x8 af[4], bfr[4];
#pragma unroll
    for (int mi = 0; mi < 4; ++mi)
      af[mi] = *reinterpret_cast<const bf16x8*>(As + (wr * 64 + mi * 16 + r16) * BK + 8 * g);
#pragma unroll
    for (int ni = 0; ni < 4; ++ni)
      bfr[ni] = *reinterpret_cast<const bf16x8*>(Bs + (wc * 64 + ni * 16 + r16) * BK + 8 * g);
#pragma unroll
    for (int mi = 0; mi < 4; ++mi)
#pragma unroll
      for (int ni = 0; ni < 4; ++ni)
        acc[mi][ni] = __builtin_amdgcn_mfma_f32_16x16x32_bf16(af[mi], bfr[ni], acc[mi][ni], 0, 0, 0);
  }

#pragma unroll
  for (int mi = 0; mi < 4; ++mi) {
#pragma unroll
    for (int ni = 0; ni < 4; ++ni) {
      const int gn = n0 + wc * 64 + ni * 16 + r16;
      const float bv = bias[gn];
#pragma unroll
      for (int r = 0; r < 4; ++r) {
        const int gm = m0 + wr * 64 + mi * 16 + g * 4 + r;
        float val = acc[mi][ni][r] + bv;
        if (MODE == 0) {
          const int which = gn >> 10;
          const int d = gn & 63;
          const int srow = gm & (S_ - 1);
          if (which < 2) {
            const float cs = costab[srow * 32 + (d >> 1)];
            const float sn = sintab[srow * 32 + (d >> 1)];
            const float pv = __shfl_xor(val, 1);
            val = (d & 1) ? (val * cs + pv * sn) : (val * cs - pv * sn);
          }
          if (which == 0) val *= QSCALE_;
          const int b = gm >> 11;
          const int h = (gn >> 6) & 15;
          bf16* dst = which == 0 ? Qo : (which == 1 ? Ko : Vo);
          dst[(((size_t)(b * H_ + h)) * S_ + srow) * D_ + d] = __float2bfloat16(val);
        } else {
          outF[(size_t)gm * 1024 + gn] = val;
        }
      }
    }
  }
}

// ---------------- causal flash attention v3 ----------------
// Q pre-scaled by 1/sqrt(d)*log2e. Q,K,V: [B*H][S][64] bf16. Out: [b][s][h*64+d] bf16.
// 256 blocks: block = (pair p, head bh); processes qblks {15-p, p} -> uniform 34 KV-tiles.
// 4 waves x 32 q-rows, KV tile 64, double-buffered LDS, 1 barrier/tile (2-phase pipeline).
__global__ __launch_bounds__(256)
void attn_kernel(const bf16* __restrict__ Q, const bf16* __restrict__ Kg,
                 const bf16* __restrict__ V, bf16* __restrict__ Og)
{
  __shared__ __align__(16) bf16 Ks[2][64 * 64];    // linear rows, xor-swizzled global source
  __shared__ __align__(16) bf16 Vt[2][64 * 72];    // V^T: (d,k): d*72 + ((k>>3)^((d>>3)&7))*8 + (k&7)
  __shared__ __align__(16) bf16 Pl[4][16][72];     // per-wave P staging
  const int flat = blockIdx.x;
  const int bh = flat & 31;                        // flat%8 == bh%8 -> same bh on same XCD
  const int pairid = flat >> 5;                    // 0..7
  const int tid = threadIdx.x, lane = tid & 63, wid = tid >> 6;
  const int g = lane >> 4, r16 = lane & 15;
  const size_t base = (size_t)bh * S_ * D_;
  const bf16* Qb = Q + base;
  const bf16* Kb = Kg + base;
  const bf16* Vb = V + base;
  const int b = bh >> 4, h = bh & 15;
  bf16* Ob = Og + (size_t)b * S_ * E_ + h * D_;

  const int vrow = tid >> 3, vc = tid & 7;         // 32 rows x 8 chunks per half-tile
  const int kc0 = tid, kc1 = 256 + tid;            // K: 512 16B-chunks
  const f32x4 fz = {0.f, 0.f, 0.f, 0.f};

  for (int phase = 0; phase < 2; ++phase) {
    const int qblk = phase == 0 ? (15 - pairid) : pairid;
    const int q0 = qblk * 128;
    const int qw0 = q0 + wid * 32;
    const int nkt = 2 * qblk + 2;

    bf16x8 qf[2][2];
#pragma unroll
    for (int mi = 0; mi < 2; ++mi)
#pragma unroll
      for (int hh = 0; hh < 2; ++hh)
        qf[mi][hh] = *reinterpret_cast<const bf16x8*>(
            Qb + (size_t)(qw0 + mi * 16 + r16) * 64 + hh * 32 + 8 * g);

    f32x4 oacc[2][4];
#pragma unroll
    for (int mi = 0; mi < 2; ++mi)
#pragma unroll
      for (int dt = 0; dt < 4; ++dt) oacc[mi][dt] = fz;
    float mrow[2][4], lrow[2][4];
#pragma unroll
    for (int mi = 0; mi < 2; ++mi)
#pragma unroll
      for (int r = 0; r < 4; ++r) { mrow[mi][r] = -__builtin_inff(); lrow[mi][r] = 0.f; }

    // ---- prologue: stage tile 0 into buffer 0 ----
    {
      const int r0 = kc0 >> 3, cc0 = kc0 & 7;
      gload_lds16(Kb + (size_t)(0 + r0) * 64 + ((cc0 ^ (r0 & 7)) * 8), &Ks[0][kc0 * 8]);
      const int r1 = kc1 >> 3, cc1 = kc1 & 7;
      gload_lds16(Kb + (size_t)(0 + r1) * 64 + ((cc1 ^ (r1 & 7)) * 8), &Ks[0][kc1 * 8]);
      union { bf16x8 v; bf16 e[8]; } u0, u1;
      u0.v = *reinterpret_cast<const bf16x8*>(Vb + (size_t)vrow * 64 + vc * 8);
      u1.v = *reinterpret_cast<const bf16x8*>(Vb + (size_t)(32 + vrow) * 64 + vc * 8);
      const int sw0 = (vrow >> 3) ^ vc;
      const int sw1 = (4 + (vrow >> 3)) ^ vc;
#pragma unroll
      for (int j = 0; j < 8; ++j) Vt[0][(vc * 8 + j) * 72 + sw0 * 8 + (vrow & 7)] = u0.e[j];
#pragma unroll
      for (int j = 0; j < 8; ++j) Vt[0][(vc * 8 + j) * 72 + sw1 * 8 + (vrow & 7)] = u1.e[j];
    }
    __syncthreads();
    int cur = 0;

    for (int kt = 0; kt < nkt; ++kt) {
      const int k0 = kt * 64;
      const bool more = (kt + 1 < nkt);
      // ---- issue next tile's loads (land during compute; drained at end barrier) ----
      union { bf16x8 v; bf16 e[8]; } un0, un1;
      if (more) {
        const int kn = k0 + 64;
        const int r0 = kc0 >> 3, cc0 = kc0 & 7;
        gload_lds16(Kb + (size_t)(kn + r0) * 64 + ((cc0 ^ (r0 & 7)) * 8), &Ks[cur ^ 1][kc0 * 8]);
        const int r1 = kc1 >> 3, cc1 = kc1 & 7;
        gload_lds16(Kb + (size_t)(kn + r1) * 64 + ((cc1 ^ (r1 & 7)) * 8), &Ks[cur ^ 1][kc1 * 8]);
        un0.v = *reinterpret_cast<const bf16x8*>(Vb + (size_t)(kn + vrow) * 64 + vc * 8);
        un1.v = *reinterpret_cast<const bf16x8*>(Vb + (size_t)(kn + 32 + vrow) * 64 + vc * 8);
      }

      // ---- compute current tile ----
      if (k0 <= qw0 + 31) {
        const bf16* ksp = Ks[cur];
        const bf16* vtp = Vt[cur];
        bf16x8 kfr[4][2];
        const int sw = r16 & 7;
#pragma unroll
        for (int kf = 0; kf < 4; ++kf) {
          const int krow = kf * 16 + r16;
          kfr[kf][0] = *reinterpret_cast<const bf16x8*>(&ksp[krow * 64 + ((g ^ sw) * 8)]);
          kfr[kf][1] = *reinterpret_cast<const bf16x8*>(&ksp[krow * 64 + (((g + 4) ^ sw) * 8)]);
        }
        f32x4 ps[2][4];
#pragma unroll
        for (int mi = 0; mi < 2; ++mi)
#pragma unroll
          for (int kf = 0; kf < 4; ++kf) {
            f32x4 sa = fz;
            sa = __builtin_amdgcn_mfma_f32_16x16x32_bf16(qf[mi][0], kfr[kf][0], sa, 0, 0, 0);
            sa = __builtin_amdgcn_mfma_f32_16x16x32_bf16(qf[mi][1], kfr[kf][1], sa, 0, 0, 0);
            ps[mi][kf] = sa;
          }
        if (k0 + 63 > qw0) {
#pragma unroll
          for (int mi = 0; mi < 2; ++mi)
#pragma unroll
            for (int kf = 0; kf < 4; ++kf)
#pragma unroll
              for (int r = 0; r < 4; ++r) {
                const int qrow = qw0 + mi * 16 + g * 4 + r;
                const int kcol = k0 + kf * 16 + r16;
                if (kcol > qrow) ps[mi][kf][r] = -1e30f;
              }
        }
#pragma unroll
        for (int mi = 0; mi < 2; ++mi) {
          float mn[4], scl[4];
#pragma unroll
          for (int r = 0; r < 4; ++r) {
            float v = fmaxf(fmaxf(ps[mi][0][r], ps[mi][1][r]), fmaxf(ps[mi][2][r], ps[mi][3][r]));
            v = fmaxf(v, __shfl_xor(v, 1));
            v = fmaxf(v, __shfl_xor(v, 2));
            v = fmaxf(v, __shfl_xor(v, 4));
            v = fmaxf(v, __shfl_xor(v, 8));
            mn[r] = fmaxf(mrow[mi][r], v);
            scl[r] = exp2f(mrow[mi][r] - mn[r]);
            mrow[mi][r] = mn[r];
          }
#pragma unroll
          for (int r = 0; r < 4; ++r) {
            float s = 0.f;
#pragma unroll
            for (int kf = 0; kf < 4; ++kf) {
              float p = exp2f(ps[mi][kf][r] - mn[r]);
              ps[mi][kf][r] = p;
              s += p;
            }
            s += __shfl_xor(s, 1);
            s += __shfl_xor(s, 2);
            s += __shfl_xor(s, 4);
            s += __shfl_xor(s, 8);
            lrow[mi][r] = lrow[mi][r] * scl[r] + s;
          }
#pragma unroll
          for (int dt = 0; dt < 4; ++dt)
#pragma unroll
            for (int r = 0; r < 4; ++r) oacc[mi][dt][r] *= scl[r];
#pragma unroll
          for (int kf = 0; kf < 4; ++kf)
#pragma unroll
            for (int r = 0; r < 4; ++r)
              Pl[wid][g * 4 + r][kf * 16 + r16] = __float2bfloat16(ps[mi][kf][r]);
          asm volatile("s_waitcnt lgkmcnt(0)" ::: "memory");
#pragma unroll
          for (int ks = 0; ks < 2; ++ks) {
            const bf16x8 pa = *reinterpret_cast<const bf16x8*>(&Pl[wid][r16][ks * 32 + g * 8]);
#pragma unroll
            for (int dt = 0; dt < 4; ++dt) {
              const int d = dt * 16 + r16;
              const bf16x8 vf = *reinterpret_cast<const bf16x8*>(
                  &vtp[d * 72 + (((ks * 4 + g) ^ ((d >> 3) & 7)) * 8)]);
              oacc[mi][dt] = __builtin_amdgcn_mfma_f32_16x16x32_bf16(pa, vf, oacc[mi][dt], 0, 0, 0);
            }
          }
        }
      }

      // ---- write next tile's V^T (reg loads have had the whole compute to land) ----
      if (more) {
        const int sw0 = (vrow >> 3) ^ vc;
        const int sw1 = (4 + (vrow >> 3)) ^ vc;
#pragma unroll
        for (int j = 0; j < 8; ++j)
          Vt[cur ^ 1][(vc * 8 + j) * 72 + sw0 * 8 + (vrow & 7)] = un0.e[j];
#pragma unroll
        for (int j = 0; j < 8; ++j)
          Vt[cur ^ 1][(vc * 8 + j) * 72 + sw1 * 8 + (vrow & 7)] = un1.e[j];
      }
      __syncthreads();
      cur ^= 1;
    }

    // ---- normalize + store ----
#pragma unroll
    for (int mi = 0; mi < 2; ++mi)
#pragma unroll
      for (int dt = 0; dt < 4; ++dt)
#pragma unroll
        for (int r = 0; r < 4; ++r) {
          const int qrow = qw0 + mi * 16 + g * 4 + r;
          const float ov = oacc[mi][dt][r] / lrow[mi][r];
          Ob[(size_t)qrow * E_ + dt * 16 + r16] = __float2bfloat16(ov);
        }
  }
}

extern "C" void kernel_launch(void* const* d_in, const int* in_sizes, int n_in,
                              void* d_out, int out_size, void* d_ws, size_t ws_size,
                              hipStream_t stream) {
  const float* x  = (const float*)d_in[0];
  const float* Wq = (const float*)d_in[1];
  const float* bq = (const float*)d_in[2];
  const float* Wk = (const float*)d_in[3];
  const float* bk = (const float*)d_in[4];
  const float* Wv = (const float*)d_in[5];
  const float* bv = (const float*)d_in[6];
  const float* Wo = (const float*)d_in[7];
  const float* bo = (const float*)d_in[8];
  float* out = (float*)d_out;

  char* ws = (char*)d_ws;
  size_t off = 0;
  auto alloc = [&](size_t bytes) -> char* {
    char* p = ws + off; off += (bytes + 255) & ~(size_t)255; return p;
  };
  bf16* xb    = (bf16*)alloc((size_t)M_ * E_ * 2);
  bf16* Wqkvb = (bf16*)alloc((size_t)3 * E_ * E_ * 2);
  bf16* Wob   = (bf16*)alloc((size_t)E_ * E_ * 2);
  float* bqkv = (float*)alloc((size_t)3 * E_ * 4);
  bf16* Qb    = (bf16*)alloc((size_t)M_ * E_ * 2);   // [b][h][s][d]
  bf16* Kb    = (bf16*)alloc((size_t)M_ * E_ * 2);
  bf16* Vb    = (bf16*)alloc((size_t)M_ * E_ * 2);
  bf16* AOb   = (bf16*)alloc((size_t)M_ * E_ * 2);   // [b][s][e]
  float* sintab = (float*)alloc((size_t)S_ * 32 * 4);
  float* costab = (float*)alloc((size_t)S_ * 32 * 4);

  cast_kernel<<<M_ * E_ / 4 / 256, 256, 0, stream>>>(x, xb, M_ * E_ / 4);
  cast_kernel<<<E_ * E_ / 4 / 256, 256, 0, stream>>>(Wo, Wob, E_ * E_ / 4);
  cast3_kernel<<<(3 * E_ * E_ / 4 + 768 + 255) / 256, 256, 0, stream>>>(
      Wq, Wk, Wv, bq, bk, bv, Wqkvb, bqkv);
  rope_table_kernel<<<S_ * 32 / 256, 256, 0, stream>>>(sintab, costab);

  gemm_kernel<0><<<dim3(24, 32), 256, 0, stream>>>(xb, Wqkvb, bqkv, Qb, Kb, Vb,
                                                   nullptr, sintab, costab);
  attn_kernel<<<dim3(256), 256, 0, stream>>>(Qb, Kb, Vb, AOb);
  gemm_kernel<1><<<dim3(8, 32), 256, 0, stream>>>(AOb, Wob, bo, nullptr, nullptr, nullptr,
                                                  out, nullptr, nullptr);
}

// Round 4
// 162.188 us; speedup vs baseline: 2.0306x; 1.1877x over previous
//
#include <hip/hip_runtime.h>
#include <hip/hip_bf16.h>
#include <cstdint>
#include <cstddef>

typedef __hip_bfloat16 bf16;
typedef __attribute__((ext_vector_type(8))) short bf16x8;
typedef __attribute__((ext_vector_type(4))) float f32x4;

#define AS1C(p) ((const __attribute__((address_space(1))) void*)(p))
#define AS3(p)  ((__attribute__((address_space(3))) void*)(p))

constexpr int B_ = 2, S_ = 2048, E_ = 1024, H_ = 16, D_ = 64;
constexpr int M_ = B_ * S_;                      // 4096
constexpr float QSCALE_ = 0.125f * 1.44269504088896340736f;  // 1/sqrt(64) * log2(e)

__device__ __forceinline__ void gload_lds16(const bf16* g, bf16* l) {
  __builtin_amdgcn_global_load_lds(AS1C(g), AS3(l), 16, 0, 0);
}

// ---------------- cast f32 -> bf16, 4 elems/thread ----------------
__global__ void cast_kernel(const float* __restrict__ in, bf16* __restrict__ out, int n4) {
  int i = blockIdx.x * blockDim.x + threadIdx.x;
  if (i >= n4) return;
  float4 v = reinterpret_cast<const float4*>(in)[i];
  union { bf16 b[4]; short4 s; } u;
  u.b[0] = __float2bfloat16(v.x);
  u.b[1] = __float2bfloat16(v.y);
  u.b[2] = __float2bfloat16(v.z);
  u.b[3] = __float2bfloat16(v.w);
  reinterpret_cast<short4*>(out)[i] = u.s;
}

// ---------------- cast Wq|Wk|Wv into one buffer + concat biases ----------------
__global__ void cast3_kernel(const float* __restrict__ Wq, const float* __restrict__ Wk,
                             const float* __restrict__ Wv,
                             const float* __restrict__ bq, const float* __restrict__ bk,
                             const float* __restrict__ bv,
                             bf16* __restrict__ Wqkv, float* __restrict__ bqkv) {
  const int i = blockIdx.x * 256 + threadIdx.x;
  const int wn4 = 3 * E_ * E_ / 4;               // 786432
  if (i < wn4) {
    const int which = i >> 18;                   // E_*E_/4 = 2^18
    const int j = i & ((1 << 18) - 1);
    const float* src = which == 0 ? Wq : (which == 1 ? Wk : Wv);
    float4 v = reinterpret_cast<const float4*>(src)[j];
    union { bf16 b[4]; short4 s; } u;
    u.b[0] = __float2bfloat16(v.x);
    u.b[1] = __float2bfloat16(v.y);
    u.b[2] = __float2bfloat16(v.z);
    u.b[3] = __float2bfloat16(v.w);
    reinterpret_cast<short4*>(Wqkv)[i] = u.s;
  } else {
    const int j = i - wn4;
    if (j < 768) {
      const int which = j >> 8;
      const int jj = j & 255;
      const float* src = which == 0 ? bq : (which == 1 ? bk : bv);
      reinterpret_cast<float4*>(bqkv)[j] = reinterpret_cast<const float4*>(src)[jj];
    }
  }
}

// ---------------- RoPE sin/cos tables: [S][32] ----------------
__global__ void rope_table_kernel(float* __restrict__ sintab, float* __restrict__ costab) {
  int idx = blockIdx.x * blockDim.x + threadIdx.x;
  int s = idx >> 5, i = idx & 31;
  float inv = powf(10000.0f, -(float)i / 32.0f);
  float ang = (float)s * inv;
  sintab[idx] = sinf(ang);
  costab[idx] = cosf(ang);
}

// ---------------- GEMM: C = A(M x 1024) * W^T (W is N x K) + bias ----------------
// MODE 0: fused QKV (N=3072): rope on q/k, scale q by QSCALE_, scatter bf16 to [b][h][s][d]
// MODE 1: final O-proj (N=1024): write f32 [m][n]
template<int MODE>
__global__ __launch_bounds__(256)
void gemm_kernel(const bf16* __restrict__ A, const bf16* __restrict__ W,
                 const float* __restrict__ bias,
                 bf16* __restrict__ Qo, bf16* __restrict__ Ko, bf16* __restrict__ Vo,
                 float* __restrict__ outF,
                 const float* __restrict__ sintab, const float* __restrict__ costab)
{
  constexpr int K = 1024, BK = 32;
  __shared__ __align__(16) bf16 As[128 * BK];
  __shared__ __align__(16) bf16 Bs[128 * BK];
  const int tid = threadIdx.x;
  const int lane = tid & 63, wid = tid >> 6;
  const int g = lane >> 4, r16 = lane & 15;
  const int wr = wid >> 1, wc = wid & 1;

  // bijective XCD swizzle
  const int nwg = gridDim.x * gridDim.y;           // divisible by 8
  const int flat = blockIdx.y * gridDim.x + blockIdx.x;
  const int cpx = nwg >> 3;
  const int f2 = (flat & 7) * cpx + (flat >> 3);
  const int m0 = (f2 / gridDim.x) * 128, n0 = (f2 % gridDim.x) * 128;

  const f32x4 fz = {0.f, 0.f, 0.f, 0.f};
  f32x4 acc[4][4];
#pragma unroll
  for (int mi = 0; mi < 4; ++mi)
#pragma unroll
    for (int ni = 0; ni < 4; ++ni) acc[mi][ni] = fz;

  const bf16* Abase = A + (size_t)m0 * K;
  const bf16* Wbase = W + (size_t)n0 * K;
  const int c0 = tid, c1 = 256 + tid;

  for (int k0 = 0; k0 < K; k0 += BK) {
    __syncthreads();
    gload_lds16(Abase + (size_t)(c0 >> 2) * K + k0 + (c0 & 3) * 8, As + c0 * 8);
    gload_lds16(Abase + (size_t)(c1 >> 2) * K + k0 + (c1 & 3) * 8, As + c1 * 8);
    gload_lds16(Wbase + (size_t)(c0 >> 2) * K + k0 + (c0 & 3) * 8, Bs + c0 * 8);
    gload_lds16(Wbase + (size_t)(c1 >> 2) * K + k0 + (c1 & 3) * 8, Bs + c1 * 8);
    __syncthreads();

    bf16x8 af[4], bfr[4];
#pragma unroll
    for (int mi = 0; mi < 4; ++mi)
      af[mi] = *reinterpret_cast<const bf16x8*>(As + (wr * 64 + mi * 16 + r16) * BK + 8 * g);
#pragma unroll
    for (int ni = 0; ni < 4; ++ni)
      bfr[ni] = *reinterpret_cast<const bf16x8*>(Bs + (wc * 64 + ni * 16 + r16) * BK + 8 * g);
#pragma unroll
    for (int mi = 0; mi < 4; ++mi)
#pragma unroll
      for (int ni = 0; ni < 4; ++ni)
        acc[mi][ni] = __builtin_amdgcn_mfma_f32_16x16x32_bf16(af[mi], bfr[ni], acc[mi][ni], 0, 0, 0);
  }

#pragma unroll
  for (int mi = 0; mi < 4; ++mi) {
#pragma unroll
    for (int ni = 0; ni < 4; ++ni) {
      const int gn = n0 + wc * 64 + ni * 16 + r16;
      const float bv = bias[gn];
#pragma unroll
      for (int r = 0; r < 4; ++r) {
        const int gm = m0 + wr * 64 + mi * 16 + g * 4 + r;
        float val = acc[mi][ni][r] + bv;
        if (MODE == 0) {
          const int which = gn >> 10;
          const int d = gn & 63;
          const int srow = gm & (S_ - 1);
          if (which < 2) {
            const float cs = costab[srow * 32 + (d >> 1)];
            const float sn = sintab[srow * 32 + (d >> 1)];
            const float pv = __shfl_xor(val, 1);
            val = (d & 1) ? (val * cs + pv * sn) : (val * cs - pv * sn);
          }
          if (which == 0) val *= QSCALE_;
          const int b = gm >> 11;
          const int h = (gn >> 6) & 15;
          bf16* dst = which == 0 ? Qo : (which == 1 ? Ko : Vo);
          dst[(((size_t)(b * H_ + h)) * S_ + srow) * D_ + d] = __float2bfloat16(val);
        } else {
          outF[(size_t)gm * 1024 + gn] = val;
        }
      }
    }
  }
}

// ---------------- causal flash attention v4 ----------------
// Q pre-scaled by 1/sqrt(d)*log2e. Q,K,V: [B*H][S][64] bf16. Out: [b][s][h*64+d] bf16.
// 512 blocks: block = (pair p, head bh); qblks {31-p, p} of 64 rows -> uniform 34 KV-tiles.
// 4 waves x 16 q-rows, KV tile 64, double-buffered LDS, 1 barrier/tile, defer-max softmax.
__global__ __launch_bounds__(256)
void attn_kernel(const bf16* __restrict__ Q, const bf16* __restrict__ Kg,
                 const bf16* __restrict__ V, bf16* __restrict__ Og)
{
  __shared__ __align__(16) bf16 Ks[2][64 * 64];    // linear rows, xor-swizzled global source
  __shared__ __align__(16) bf16 Vt[2][64 * 72];    // V^T: (d,k): d*72 + ((k>>3)^((d>>3)&7))*8 + (k&7)
  __shared__ __align__(16) bf16 Pl[4][16][72];     // per-wave P staging
  const int flat = blockIdx.x;
  const int bh = flat & 31;                        // flat%8 == bh%8 -> same bh on same XCD
  const int pairid = flat >> 5;                    // 0..15
  const int tid = threadIdx.x, lane = tid & 63, wid = tid >> 6;
  const int g = lane >> 4, r16 = lane & 15;
  const size_t base = (size_t)bh * S_ * D_;
  const bf16* Qb = Q + base;
  const bf16* Kb = Kg + base;
  const bf16* Vb = V + base;
  const int b = bh >> 4, h = bh & 15;
  bf16* Ob = Og + (size_t)b * S_ * E_ + h * D_;

  const int vrow = tid >> 3, vc = tid & 7;         // 32 rows x 8 chunks per half-tile
  const int kc0 = tid, kc1 = 256 + tid;            // K: 512 16B-chunks
  const f32x4 fz = {0.f, 0.f, 0.f, 0.f};

  for (int phase = 0; phase < 2; ++phase) {
    const int qblk = phase == 0 ? (31 - pairid) : pairid;
    const int q0 = qblk * 64;
    const int qw0 = q0 + wid * 16;
    const int nkt = qblk + 1;

    bf16x8 qf[2];
#pragma unroll
    for (int hh = 0; hh < 2; ++hh)
      qf[hh] = *reinterpret_cast<const bf16x8*>(
          Qb + (size_t)(qw0 + r16) * 64 + hh * 32 + 8 * g);

    f32x4 oacc[4];
#pragma unroll
    for (int dt = 0; dt < 4; ++dt) oacc[dt] = fz;
    float mrow[4], lrow[4];
#pragma unroll
    for (int r = 0; r < 4; ++r) { mrow[r] = -__builtin_inff(); lrow[r] = 0.f; }

    // ---- prologue: stage tile 0 into buffer 0 ----
    {
      const int r0 = kc0 >> 3, cc0 = kc0 & 7;
      gload_lds16(Kb + (size_t)r0 * 64 + ((cc0 ^ (r0 & 7)) * 8), &Ks[0][kc0 * 8]);
      const int r1 = kc1 >> 3, cc1 = kc1 & 7;
      gload_lds16(Kb + (size_t)r1 * 64 + ((cc1 ^ (r1 & 7)) * 8), &Ks[0][kc1 * 8]);
      union { bf16x8 v; bf16 e[8]; } u0, u1;
      u0.v = *reinterpret_cast<const bf16x8*>(Vb + (size_t)vrow * 64 + vc * 8);
      u1.v = *reinterpret_cast<const bf16x8*>(Vb + (size_t)(32 + vrow) * 64 + vc * 8);
      const int sw0 = (vrow >> 3) ^ vc;
      const int sw1 = (4 + (vrow >> 3)) ^ vc;
#pragma unroll
      for (int j = 0; j < 8; ++j) Vt[0][(vc * 8 + j) * 72 + sw0 * 8 + (vrow & 7)] = u0.e[j];
#pragma unroll
      for (int j = 0; j < 8; ++j) Vt[0][(vc * 8 + j) * 72 + sw1 * 8 + (vrow & 7)] = u1.e[j];
    }
    __syncthreads();
    int cur = 0;

    for (int kt = 0; kt < nkt; ++kt) {
      const int k0 = kt * 64;
      const bool more = (kt + 1 < nkt);
      // ---- issue next tile's loads ----
      union { bf16x8 v; bf16 e[8]; } un0, un1;
      if (more) {
        const int kn = k0 + 64;
        const int r0 = kc0 >> 3, cc0 = kc0 & 7;
        gload_lds16(Kb + (size_t)(kn + r0) * 64 + ((cc0 ^ (r0 & 7)) * 8), &Ks[cur ^ 1][kc0 * 8]);
        const int r1 = kc1 >> 3, cc1 = kc1 & 7;
        gload_lds16(Kb + (size_t)(kn + r1) * 64 + ((cc1 ^ (r1 & 7)) * 8), &Ks[cur ^ 1][kc1 * 8]);
        un0.v = *reinterpret_cast<const bf16x8*>(Vb + (size_t)(kn + vrow) * 64 + vc * 8);
        un1.v = *reinterpret_cast<const bf16x8*>(Vb + (size_t)(kn + 32 + vrow) * 64 + vc * 8);
      }

      // ---- compute current tile (this wave's 16 rows all >= k0?) ----
      if (k0 <= qw0 + 15) {
        const bf16* ksp = Ks[cur];
        const bf16* vtp = Vt[cur];
        bf16x8 kfr[4][2];
        const int sw = r16 & 7;
#pragma unroll
        for (int kf = 0; kf < 4; ++kf) {
          const int krow = kf * 16 + r16;
          kfr[kf][0] = *reinterpret_cast<const bf16x8*>(&ksp[krow * 64 + ((g ^ sw) * 8)]);
          kfr[kf][1] = *reinterpret_cast<const bf16x8*>(&ksp[krow * 64 + (((g + 4) ^ sw) * 8)]);
        }
        f32x4 ps[4];
#pragma unroll
        for (int kf = 0; kf < 4; ++kf) {
          f32x4 sa = fz;
          sa = __builtin_amdgcn_mfma_f32_16x16x32_bf16(qf[0], kfr[kf][0], sa, 0, 0, 0);
          sa = __builtin_amdgcn_mfma_f32_16x16x32_bf16(qf[1], kfr[kf][1], sa, 0, 0, 0);
          ps[kf] = sa;
        }
        if (k0 + 63 > qw0) {
#pragma unroll
          for (int kf = 0; kf < 4; ++kf)
#pragma unroll
            for (int r = 0; r < 4; ++r) {
              const int qrow = qw0 + g * 4 + r;
              const int kcol = k0 + kf * 16 + r16;
              if (kcol > qrow) ps[kf][r] = -1e30f;
            }
        }
        // ---- defer-max online softmax (base-2 domain) ----
        float tm[4];
#pragma unroll
        for (int r = 0; r < 4; ++r) {
          float v = fmaxf(fmaxf(ps[0][r], ps[1][r]), fmaxf(ps[2][r], ps[3][r]));
          v = fmaxf(v, __shfl_xor(v, 1));
          v = fmaxf(v, __shfl_xor(v, 2));
          v = fmaxf(v, __shfl_xor(v, 4));
          v = fmaxf(v, __shfl_xor(v, 8));
          tm[r] = v;
        }
        bool need = false;
#pragma unroll
        for (int r = 0; r < 4; ++r) need = need || (tm[r] - mrow[r] > 8.f);
        if (__any(need ? 1 : 0)) {
#pragma unroll
          for (int r = 0; r < 4; ++r) {
            const float mn = fmaxf(mrow[r], tm[r]);
            const float scl = exp2f(mrow[r] - mn);
            mrow[r] = mn;
            lrow[r] *= scl;
#pragma unroll
            for (int dt = 0; dt < 4; ++dt) oacc[dt][r] *= scl;
          }
        }
#pragma unroll
        for (int r = 0; r < 4; ++r) {
          float s = 0.f;
#pragma unroll
          for (int kf = 0; kf < 4; ++kf) {
            float p = exp2f(ps[kf][r] - mrow[r]);
            ps[kf][r] = p;
            s += p;
          }
          s += __shfl_xor(s, 1);
          s += __shfl_xor(s, 2);
          s += __shfl_xor(s, 4);
          s += __shfl_xor(s, 8);
          lrow[r] += s;
        }
        // ---- P -> LDS (D-layout) -> A-fragment layout ----
#pragma unroll
        for (int kf = 0; kf < 4; ++kf)
#pragma unroll
          for (int r = 0; r < 4; ++r)
            Pl[wid][g * 4 + r][kf * 16 + r16] = __float2bfloat16(ps[kf][r]);
        asm volatile("s_waitcnt lgkmcnt(0)" ::: "memory");
#pragma unroll
        for (int ks = 0; ks < 2; ++ks) {
          const bf16x8 pa = *reinterpret_cast<const bf16x8*>(&Pl[wid][r16][ks * 32 + g * 8]);
#pragma unroll
          for (int dt = 0; dt < 4; ++dt) {
            const int d = dt * 16 + r16;
            const bf16x8 vf = *reinterpret_cast<const bf16x8*>(
                &vtp[d * 72 + (((ks * 4 + g) ^ ((d >> 3) & 7)) * 8)]);
            oacc[dt] = __builtin_amdgcn_mfma_f32_16x16x32_bf16(pa, vf, oacc[dt], 0, 0, 0);
          }
        }
      }

      // ---- write next tile's V^T ----
      if (more) {
        const int sw0 = (vrow >> 3) ^ vc;
        const int sw1 = (4 + (vrow >> 3)) ^ vc;
#pragma unroll
        for (int j = 0; j < 8; ++j)
          Vt[cur ^ 1][(vc * 8 + j) * 72 + sw0 * 8 + (vrow & 7)] = un0.e[j];
#pragma unroll
        for (int j = 0; j < 8; ++j)
          Vt[cur ^ 1][(vc * 8 + j) * 72 + sw1 * 8 + (vrow & 7)] = un1.e[j];
      }
      __syncthreads();
      cur ^= 1;
    }

    // ---- normalize + store ----
#pragma unroll
    for (int dt = 0; dt < 4; ++dt)
#pragma unroll
      for (int r = 0; r < 4; ++r) {
        const int qrow = qw0 + g * 4 + r;
        const float ov = oacc[dt][r] / lrow[r];
        Ob[(size_t)qrow * E_ + dt * 16 + r16] = __float2bfloat16(ov);
      }
  }
}

extern "C" void kernel_launch(void* const* d_in, const int* in_sizes, int n_in,
                              void* d_out, int out_size, void* d_ws, size_t ws_size,
                              hipStream_t stream) {
  const float* x  = (const float*)d_in[0];
  const float* Wq = (const float*)d_in[1];
  const float* bq = (const float*)d_in[2];
  const float* Wk = (const float*)d_in[3];
  const float* bk = (const float*)d_in[4];
  const float* Wv = (const float*)d_in[5];
  const float* bv = (const float*)d_in[6];
  const float* Wo = (const float*)d_in[7];
  const float* bo = (const float*)d_in[8];
  float* out = (float*)d_out;

  char* ws = (char*)d_ws;
  size_t off = 0;
  auto alloc = [&](size_t bytes) -> char* {
    char* p = ws + off; off += (bytes + 255) & ~(size_t)255; return p;
  };
  bf16* xb    = (bf16*)alloc((size_t)M_ * E_ * 2);
  bf16* Wqkvb = (bf16*)alloc((size_t)3 * E_ * E_ * 2);
  bf16* Wob   = (bf16*)alloc((size_t)E_ * E_ * 2);
  float* bqkv = (float*)alloc((size_t)3 * E_ * 4);
  bf16* Qb    = (bf16*)alloc((size_t)M_ * E_ * 2);   // [b][h][s][d]
  bf16* Kb    = (bf16*)alloc((size_t)M_ * E_ * 2);
  bf16* Vb    = (bf16*)alloc((size_t)M_ * E_ * 2);
  bf16* AOb   = (bf16*)alloc((size_t)M_ * E_ * 2);   // [b][s][e]
  float* sintab = (float*)alloc((size_t)S_ * 32 * 4);
  float* costab = (float*)alloc((size_t)S_ * 32 * 4);

  cast_kernel<<<M_ * E_ / 4 / 256, 256, 0, stream>>>(x, xb, M_ * E_ / 4);
  cast_kernel<<<E_ * E_ / 4 / 256, 256, 0, stream>>>(Wo, Wob, E_ * E_ / 4);
  cast3_kernel<<<(3 * E_ * E_ / 4 + 768 + 255) / 256, 256, 0, stream>>>(
      Wq, Wk, Wv, bq, bk, bv, Wqkvb, bqkv);
  rope_table_kernel<<<S_ * 32 / 256, 256, 0, stream>>>(sintab, costab);

  gemm_kernel<0><<<dim3(24, 32), 256, 0, stream>>>(xb, Wqkvb, bqkv, Qb, Kb, Vb,
                                                   nullptr, sintab, costab);
  attn_kernel<<<dim3(512), 256, 0, stream>>>(Qb, Kb, Vb, AOb);
  gemm_kernel<1><<<dim3(8, 32), 256, 0, stream>>>(AOb, Wob, bo, nullptr, nullptr, nullptr,
                                                  out, nullptr, nullptr);
}

// Round 5
// 144.876 us; speedup vs baseline: 2.2732x; 1.1195x over previous
//
#include <hip/hip_runtime.h>
#include <hip/hip_bf16.h>
#include <cstdint>
#include <cstddef>

typedef __hip_bfloat16 bf16;
typedef __attribute__((ext_vector_type(8))) short bf16x8;
typedef __attribute__((ext_vector_type(4))) float f32x4;

#define AS1C(p) ((const __attribute__((address_space(1))) void*)(p))
#define AS3(p)  ((__attribute__((address_space(3))) void*)(p))

constexpr int B_ = 2, S_ = 2048, E_ = 1024, H_ = 16, D_ = 64;
constexpr int M_ = B_ * S_;                      // 4096
constexpr float QSCALE_ = 0.125f * 1.44269504088896340736f;  // 1/sqrt(64) * log2(e)

__device__ __forceinline__ void gload_lds16(const bf16* g, bf16* l) {
  __builtin_amdgcn_global_load_lds(AS1C(g), AS3(l), 16, 0, 0);
}

__device__ __forceinline__ void cast4(const float* __restrict__ in, bf16* __restrict__ out, int i) {
  float4 v = reinterpret_cast<const float4*>(in)[i];
  union { bf16 b[4]; short4 s; } u;
  u.b[0] = __float2bfloat16(v.x);
  u.b[1] = __float2bfloat16(v.y);
  u.b[2] = __float2bfloat16(v.z);
  u.b[3] = __float2bfloat16(v.w);
  reinterpret_cast<short4*>(out)[i] = u.s;
}

// ---------------- fused prep: casts + rope tables + bias concat (1 launch) ----------------
// blocks [0,4096): x cast | [4096,5120): Wo | [5120,8192): Wqkv | [8192,8448): rope | 8448: biases
__global__ void prep_kernel(const float* __restrict__ x,
                            const float* __restrict__ Wq, const float* __restrict__ Wk,
                            const float* __restrict__ Wv, const float* __restrict__ Wo,
                            const float* __restrict__ bq, const float* __restrict__ bk,
                            const float* __restrict__ bv,
                            bf16* __restrict__ xb, bf16* __restrict__ Wqkvb,
                            bf16* __restrict__ Wob, float* __restrict__ bqkv,
                            float* __restrict__ sintab, float* __restrict__ costab) {
  const int b = blockIdx.x, t = threadIdx.x;
  if (b < 4096) {
    cast4(x, xb, b * 256 + t);
  } else if (b < 5120) {
    cast4(Wo, Wob, (b - 4096) * 256 + t);
  } else if (b < 8192) {
    const int i = (b - 5120) * 256 + t;          // 0..786431
    const int which = i >> 18;
    const int j = i & ((1 << 18) - 1);
    const float* src = which == 0 ? Wq : (which == 1 ? Wk : Wv);
    cast4(src, Wqkvb + (size_t)which * E_ * E_, j);
    // note: cast4 indexes out by i-relative; adjust: we pass base per-which and j
  } else if (b < 8448) {
    const int idx = (b - 8192) * 256 + t;        // S_*32 = 65536
    const int s = idx >> 5, i = idx & 31;
    float inv = powf(10000.0f, -(float)i / 32.0f);
    float ang = (float)s * inv;
    sintab[idx] = sinf(ang);
    costab[idx] = cosf(ang);
  } else {
    for (int j = t; j < 768; j += 256) {
      const int which = j >> 8, jj = j & 255;
      const float* src = which == 0 ? bq : (which == 1 ? bk : bv);
      reinterpret_cast<float4*>(bqkv)[j] = reinterpret_cast<const float4*>(src)[jj];
    }
  }
}

// ---------------- GEMM: C = A(M x 1024) * W^T (W is N x K) + bias ----------------
// MODE 0: fused QKV (N=3072): rope on q/k, scale q by QSCALE_, scatter bf16 to [b][h][s][d]
// MODE 1: final O-proj (N=1024): write f32 [m][n]
template<int MODE>
__global__ __launch_bounds__(256)
void gemm_kernel(const bf16* __restrict__ A, const bf16* __restrict__ W,
                 const float* __restrict__ bias,
                 bf16* __restrict__ Qo, bf16* __restrict__ Ko, bf16* __restrict__ Vo,
                 float* __restrict__ outF,
                 const float* __restrict__ sintab, const float* __restrict__ costab)
{
  constexpr int K = 1024, BK = 32;
  __shared__ __align__(16) bf16 As[128 * BK];
  __shared__ __align__(16) bf16 Bs[128 * BK];
  const int tid = threadIdx.x;
  const int lane = tid & 63, wid = tid >> 6;
  const int g = lane >> 4, r16 = lane & 15;
  const int wr = wid >> 1, wc = wid & 1;

  // bijective XCD swizzle
  const int nwg = gridDim.x * gridDim.y;           // divisible by 8
  const int flat = blockIdx.y * gridDim.x + blockIdx.x;
  const int cpx = nwg >> 3;
  const int f2 = (flat & 7) * cpx + (flat >> 3);
  const int m0 = (f2 / gridDim.x) * 128, n0 = (f2 % gridDim.x) * 128;

  const f32x4 fz = {0.f, 0.f, 0.f, 0.f};
  f32x4 acc[4][4];
#pragma unroll
  for (int mi = 0; mi < 4; ++mi)
#pragma unroll
    for (int ni = 0; ni < 4; ++ni) acc[mi][ni] = fz;

  const bf16* Abase = A + (size_t)m0 * K;
  const bf16* Wbase = W + (size_t)n0 * K;
  const int c0 = tid, c1 = 256 + tid;

  for (int k0 = 0; k0 < K; k0 += BK) {
    __syncthreads();
    gload_lds16(Abase + (size_t)(c0 >> 2) * K + k0 + (c0 & 3) * 8, As + c0 * 8);
    gload_lds16(Abase + (size_t)(c1 >> 2) * K + k0 + (c1 & 3) * 8, As + c1 * 8);
    gload_lds16(Wbase + (size_t)(c0 >> 2) * K + k0 + (c0 & 3) * 8, Bs + c0 * 8);
    gload_lds16(Wbase + (size_t)(c1 >> 2) * K + k0 + (c1 & 3) * 8, Bs + c1 * 8);
    __syncthreads();

    bf16x8 af[4], bfr[4];
#pragma unroll
    for (int mi = 0; mi < 4; ++mi)
      af[mi] = *reinterpret_cast<const bf16x8*>(As + (wr * 64 + mi * 16 + r16) * BK + 8 * g);
#pragma unroll
    for (int ni = 0; ni < 4; ++ni)
      bfr[ni] = *reinterpret_cast<const bf16x8*>(Bs + (wc * 64 + ni * 16 + r16) * BK + 8 * g);
    __builtin_amdgcn_s_setprio(1);
#pragma unroll
    for (int mi = 0; mi < 4; ++mi)
#pragma unroll
      for (int ni = 0; ni < 4; ++ni)
        acc[mi][ni] = __builtin_amdgcn_mfma_f32_16x16x32_bf16(af[mi], bfr[ni], acc[mi][ni], 0, 0, 0);
    __builtin_amdgcn_s_setprio(0);
  }

#pragma unroll
  for (int mi = 0; mi < 4; ++mi) {
#pragma unroll
    for (int ni = 0; ni < 4; ++ni) {
      const int gn = n0 + wc * 64 + ni * 16 + r16;
      const float bv = bias[gn];
#pragma unroll
      for (int r = 0; r < 4; ++r) {
        const int gm = m0 + wr * 64 + mi * 16 + g * 4 + r;
        float val = acc[mi][ni][r] + bv;
        if (MODE == 0) {
          const int which = gn >> 10;
          const int d = gn & 63;
          const int srow = gm & (S_ - 1);
          if (which < 2) {
            const float cs = costab[srow * 32 + (d >> 1)];
            const float sn = sintab[srow * 32 + (d >> 1)];
            const float pv = __shfl_xor(val, 1);
            val = (d & 1) ? (val * cs + pv * sn) : (val * cs - pv * sn);
          }
          if (which == 0) val *= QSCALE_;
          const int b = gm >> 11;
          const int h = (gn >> 6) & 15;
          bf16* dst = which == 0 ? Qo : (which == 1 ? Ko : Vo);
          dst[(((size_t)(b * H_ + h)) * S_ + srow) * D_ + d] = __float2bfloat16(val);
        } else {
          outF[(size_t)gm * 1024 + gn] = val;
        }
      }
    }
  }
}

// ---------------- causal flash attention v5 ----------------
// Q pre-scaled by 1/sqrt(d)*log2e. Q,K,V: [B*H][S][64] bf16. Out: [b][s][h*64+d] bf16.
// 1024 blocks, heavy-first: flat -> (qblk = 31 - flat>>5, bh = flat&31). 64 q-rows/block,
// 4 waves x 16 rows, KV tile 64, dbuf LDS, 1 barrier/tile, defer-max, lazy l-reduce.
__global__ __launch_bounds__(256)
void attn_kernel(const bf16* __restrict__ Q, const bf16* __restrict__ Kg,
                 const bf16* __restrict__ V, bf16* __restrict__ Og)
{
  __shared__ __align__(16) bf16 Ks[2][64 * 64];    // linear rows, xor-swizzled global source
  __shared__ __align__(16) bf16 Vt[2][64 * 72];    // V^T: (d,k): d*72 + ((k>>3)^((d>>3)&7))*8 + (k&7)
  __shared__ __align__(16) bf16 Pl[4][16][72];     // per-wave P staging
  const int flat = blockIdx.x;
  const int bh = flat & 31;                        // flat%8 == bh%8 -> same heads per XCD
  const int qblk = 31 - (flat >> 5);               // heavy-first
  const int tid = threadIdx.x, lane = tid & 63, wid = tid >> 6;
  const int g = lane >> 4, r16 = lane & 15;
  const size_t base = (size_t)bh * S_ * D_;
  const bf16* Qb = Q + base;
  const bf16* Kb = Kg + base;
  const bf16* Vb = V + base;
  const int b = bh >> 4, h = bh & 15;
  bf16* Ob = Og + (size_t)b * S_ * E_ + h * D_;

  const int vrow = tid >> 3, vc = tid & 7;         // 32 rows x 8 chunks per half-tile
  const int kc0 = tid, kc1 = 256 + tid;            // K: 512 16B-chunks
  const f32x4 fz = {0.f, 0.f, 0.f, 0.f};

  const int q0 = qblk * 64;
  const int qw0 = q0 + wid * 16;
  const int nkt = qblk + 1;

  bf16x8 qf[2];
#pragma unroll
  for (int hh = 0; hh < 2; ++hh)
    qf[hh] = *reinterpret_cast<const bf16x8*>(
        Qb + (size_t)(qw0 + r16) * 64 + hh * 32 + 8 * g);

  f32x4 oacc[4];
#pragma unroll
  for (int dt = 0; dt < 4; ++dt) oacc[dt] = fz;
  float mrow[4], lrow[4];
#pragma unroll
  for (int r = 0; r < 4; ++r) { mrow[r] = -__builtin_inff(); lrow[r] = 0.f; }

  // ---- prologue: stage tile 0 into buffer 0 ----
  {
    const int r0 = kc0 >> 3, cc0 = kc0 & 7;
    gload_lds16(Kb + (size_t)r0 * 64 + ((cc0 ^ (r0 & 7)) * 8), &Ks[0][kc0 * 8]);
    const int r1 = kc1 >> 3, cc1 = kc1 & 7;
    gload_lds16(Kb + (size_t)r1 * 64 + ((cc1 ^ (r1 & 7)) * 8), &Ks[0][kc1 * 8]);
    union { bf16x8 v; bf16 e[8]; } u0, u1;
    u0.v = *reinterpret_cast<const bf16x8*>(Vb + (size_t)vrow * 64 + vc * 8);
    u1.v = *reinterpret_cast<const bf16x8*>(Vb + (size_t)(32 + vrow) * 64 + vc * 8);
    const int sw0 = (vrow >> 3) ^ vc;
    const int sw1 = (4 + (vrow >> 3)) ^ vc;
#pragma unroll
    for (int j = 0; j < 8; ++j) Vt[0][(vc * 8 + j) * 72 + sw0 * 8 + (vrow & 7)] = u0.e[j];
#pragma unroll
    for (int j = 0; j < 8; ++j) Vt[0][(vc * 8 + j) * 72 + sw1 * 8 + (vrow & 7)] = u1.e[j];
  }
  __syncthreads();
  int cur = 0;

  for (int kt = 0; kt < nkt; ++kt) {
    const int k0 = kt * 64;
    const bool more = (kt + 1 < nkt);
    // ---- issue next tile's loads ----
    union { bf16x8 v; bf16 e[8]; } un0, un1;
    if (more) {
      const int kn = k0 + 64;
      const int r0 = kc0 >> 3, cc0 = kc0 & 7;
      gload_lds16(Kb + (size_t)(kn + r0) * 64 + ((cc0 ^ (r0 & 7)) * 8), &Ks[cur ^ 1][kc0 * 8]);
      const int r1 = kc1 >> 3, cc1 = kc1 & 7;
      gload_lds16(Kb + (size_t)(kn + r1) * 64 + ((cc1 ^ (r1 & 7)) * 8), &Ks[cur ^ 1][kc1 * 8]);
      un0.v = *reinterpret_cast<const bf16x8*>(Vb + (size_t)(kn + vrow) * 64 + vc * 8);
      un1.v = *reinterpret_cast<const bf16x8*>(Vb + (size_t)(kn + 32 + vrow) * 64 + vc * 8);
    }

    // ---- compute current tile ----
    if (k0 <= qw0 + 15) {
      const bf16* ksp = Ks[cur];
      const bf16* vtp = Vt[cur];
      bf16x8 kfr[4][2];
      const int sw = r16 & 7;
#pragma unroll
      for (int kf = 0; kf < 4; ++kf) {
        const int krow = kf * 16 + r16;
        kfr[kf][0] = *reinterpret_cast<const bf16x8*>(&ksp[krow * 64 + ((g ^ sw) * 8)]);
        kfr[kf][1] = *reinterpret_cast<const bf16x8*>(&ksp[krow * 64 + (((g + 4) ^ sw) * 8)]);
      }
      f32x4 ps[4];
      __builtin_amdgcn_s_setprio(1);
#pragma unroll
      for (int kf = 0; kf < 4; ++kf) {
        f32x4 sa = fz;
        sa = __builtin_amdgcn_mfma_f32_16x16x32_bf16(qf[0], kfr[kf][0], sa, 0, 0, 0);
        sa = __builtin_amdgcn_mfma_f32_16x16x32_bf16(qf[1], kfr[kf][1], sa, 0, 0, 0);
        ps[kf] = sa;
      }
      __builtin_amdgcn_s_setprio(0);
      if (k0 + 63 > qw0) {
#pragma unroll
        for (int kf = 0; kf < 4; ++kf)
#pragma unroll
          for (int r = 0; r < 4; ++r) {
            const int qrow = qw0 + g * 4 + r;
            const int kcol = k0 + kf * 16 + r16;
            if (kcol > qrow) ps[kf][r] = -1e30f;
          }
      }
      // ---- defer-max online softmax (base-2); lrow kept as per-lane partials ----
      float tm[4];
#pragma unroll
      for (int r = 0; r < 4; ++r) {
        float v = fmaxf(fmaxf(ps[0][r], ps[1][r]), fmaxf(ps[2][r], ps[3][r]));
        v = fmaxf(v, __shfl_xor(v, 1));
        v = fmaxf(v, __shfl_xor(v, 2));
        v = fmaxf(v, __shfl_xor(v, 4));
        v = fmaxf(v, __shfl_xor(v, 8));
        tm[r] = v;
      }
      bool need = false;
#pragma unroll
      for (int r = 0; r < 4; ++r) need = need || (tm[r] - mrow[r] > 8.f);
      if (__any(need ? 1 : 0)) {
#pragma unroll
        for (int r = 0; r < 4; ++r) {
          const float mn = fmaxf(mrow[r], tm[r]);
          const float scl = exp2f(mrow[r] - mn);
          mrow[r] = mn;
          lrow[r] *= scl;
#pragma unroll
          for (int dt = 0; dt < 4; ++dt) oacc[dt][r] *= scl;
        }
      }
#pragma unroll
      for (int r = 0; r < 4; ++r) {
        float s = 0.f;
#pragma unroll
        for (int kf = 0; kf < 4; ++kf) {
          float p = exp2f(ps[kf][r] - mrow[r]);
          ps[kf][r] = p;
          s += p;
        }
        lrow[r] += s;                              // per-lane partial; reduced at epilogue
      }
      // ---- P -> LDS (D-layout) -> A-fragment layout ----
#pragma unroll
      for (int kf = 0; kf < 4; ++kf)
#pragma unroll
        for (int r = 0; r < 4; ++r)
          Pl[wid][g * 4 + r][kf * 16 + r16] = __float2bfloat16(ps[kf][r]);
      asm volatile("s_waitcnt lgkmcnt(0)" ::: "memory");
      __builtin_amdgcn_s_setprio(1);
#pragma unroll
      for (int ks = 0; ks < 2; ++ks) {
        const bf16x8 pa = *reinterpret_cast<const bf16x8*>(&Pl[wid][r16][ks * 32 + g * 8]);
#pragma unroll
        for (int dt = 0; dt < 4; ++dt) {
          const int d = dt * 16 + r16;
          const bf16x8 vf = *reinterpret_cast<const bf16x8*>(
              &vtp[d * 72 + (((ks * 4 + g) ^ ((d >> 3) & 7)) * 8)]);
          oacc[dt] = __builtin_amdgcn_mfma_f32_16x16x32_bf16(pa, vf, oacc[dt], 0, 0, 0);
        }
      }
      __builtin_amdgcn_s_setprio(0);
    }

    // ---- write next tile's V^T ----
    if (more) {
      const int sw0 = (vrow >> 3) ^ vc;
      const int sw1 = (4 + (vrow >> 3)) ^ vc;
#pragma unroll
      for (int j = 0; j < 8; ++j)
        Vt[cur ^ 1][(vc * 8 + j) * 72 + sw0 * 8 + (vrow & 7)] = un0.e[j];
#pragma unroll
      for (int j = 0; j < 8; ++j)
        Vt[cur ^ 1][(vc * 8 + j) * 72 + sw1 * 8 + (vrow & 7)] = un1.e[j];
    }
    __syncthreads();
    cur ^= 1;
  }

  // ---- final l reduce + normalize + store ----
  float linv[4];
#pragma unroll
  for (int r = 0; r < 4; ++r) {
    float s = lrow[r];
    s += __shfl_xor(s, 1);
    s += __shfl_xor(s, 2);
    s += __shfl_xor(s, 4);
    s += __shfl_xor(s, 8);
    linv[r] = 1.0f / s;
  }
#pragma unroll
  for (int dt = 0; dt < 4; ++dt)
#pragma unroll
    for (int r = 0; r < 4; ++r) {
      const int qrow = qw0 + g * 4 + r;
      const float ov = oacc[dt][r] * linv[r];
      Ob[(size_t)qrow * E_ + dt * 16 + r16] = __float2bfloat16(ov);
    }
}

extern "C" void kernel_launch(void* const* d_in, const int* in_sizes, int n_in,
                              void* d_out, int out_size, void* d_ws, size_t ws_size,
                              hipStream_t stream) {
  const float* x  = (const float*)d_in[0];
  const float* Wq = (const float*)d_in[1];
  const float* bq = (const float*)d_in[2];
  const float* Wk = (const float*)d_in[3];
  const float* bk = (const float*)d_in[4];
  const float* Wv = (const float*)d_in[5];
  const float* bv = (const float*)d_in[6];
  const float* Wo = (const float*)d_in[7];
  const float* bo = (const float*)d_in[8];
  float* out = (float*)d_out;

  char* ws = (char*)d_ws;
  size_t off = 0;
  auto alloc = [&](size_t bytes) -> char* {
    char* p = ws + off; off += (bytes + 255) & ~(size_t)255; return p;
  };
  bf16* xb    = (bf16*)alloc((size_t)M_ * E_ * 2);
  bf16* Wqkvb = (bf16*)alloc((size_t)3 * E_ * E_ * 2);
  bf16* Wob   = (bf16*)alloc((size_t)E_ * E_ * 2);
  float* bqkv = (float*)alloc((size_t)3 * E_ * 4);
  bf16* Qb    = (bf16*)alloc((size_t)M_ * E_ * 2);   // [b][h][s][d]
  bf16* Kb    = (bf16*)alloc((size_t)M_ * E_ * 2);
  bf16* Vb    = (bf16*)alloc((size_t)M_ * E_ * 2);
  bf16* AOb   = (bf16*)alloc((size_t)M_ * E_ * 2);   // [b][s][e]
  float* sintab = (float*)alloc((size_t)S_ * 32 * 4);
  float* costab = (float*)alloc((size_t)S_ * 32 * 4);

  prep_kernel<<<dim3(8449), 256, 0, stream>>>(x, Wq, Wk, Wv, Wo, bq, bk, bv,
                                              xb, Wqkvb, Wob, bqkv, sintab, costab);

  gemm_kernel<0><<<dim3(24, 32), 256, 0, stream>>>(xb, Wqkvb, bqkv, Qb, Kb, Vb,
                                                   nullptr, sintab, costab);
  attn_kernel<<<dim3(1024), 256, 0, stream>>>(Qb, Kb, Vb, AOb);
  gemm_kernel<1><<<dim3(8, 32), 256, 0, stream>>>(AOb, Wob, bo, nullptr, nullptr, nullptr,
                                                  out, nullptr, nullptr);
}